// Round 1
// baseline (1535.419 us; speedup 1.0000x reference)
//
#include <hip/hip_runtime.h>
#include <hip/hip_bf16.h>

typedef _Float16 f16x8 __attribute__((ext_vector_type(8)));
typedef float    f32x4 __attribute__((ext_vector_type(4)));

#define HW   36864   // 192*192
#define W_   192
#define NS   9216    // 96*96 patches
#define CCH  128     // channels (QK inner dim)
#define DV   512     // c*r*r  (PV output dim)

// ---------- prep: Vt[d][m] (f16, transposed patches) + F16[m][c] (f16 feat) ----------
__global__ __launch_bounds__(256) void prep_vt_kernel(const float* __restrict__ x,
        _Float16* __restrict__ Vt, _Float16* __restrict__ F16)
{
    int m = blockIdx.x * 256 + threadIdx.x;   // 0..9215
    int d = blockIdx.y;                       // 0..511
    int c = d >> 2, di = (d >> 1) & 1, dj = d & 1;
    int i = m / 96, j = m - i * 96;
    float v = x[c * HW + (2 * i + di) * W_ + (2 * j + dj)];
    _Float16 h = (_Float16)v;
    Vt[(size_t)d * NS + m] = h;
    if ((d & 3) == 0) F16[m * CCH + c] = h;   // di=dj=0 element == feat
}

// ---------- prep: csv[m] = valid ? 10/(||f_m||+eps) : 0 ----------
__global__ __launch_bounds__(64) void prep_csv_kernel(const _Float16* __restrict__ F16,
        const float* __restrict__ mask, float* __restrict__ csv)
{
    int m = blockIdx.x;
    int t = threadIdx.x;                      // one wave
    float a = (float)F16[m * CCH + 2 * t];
    float b = (float)F16[m * CCH + 2 * t + 1];
    float ss = a * a + b * b;
    #pragma unroll
    for (int off = 1; off <= 32; off <<= 1)
        ss += __shfl_xor(ss, off);
    if (t == 0) {
        int i = m / 96, j = m - i * 96;
        float ms = mask[(2 * i) * W_ + 2 * j];
        csv[m] = (ms == 0.0f) ? 10.0f / (sqrtf(ss) + 1e-8f) : 0.0f;
    }
}

// ---------- fused masked attention (flash-style, f16 MFMA) ----------
// grid 288: (rowgroup = bx>>1)*64 rows, d-half = (bx&1)*256. 4 waves: 16 rows x 256 d each.
__global__ __launch_bounds__(256) void flash_kernel(const _Float16* __restrict__ F16,
        const _Float16* __restrict__ Vt, const float* __restrict__ csv,
        float* __restrict__ recon_t)
{
    __shared__ _Float16 plds[4 * 16 * 64];    // per-wave private 16x64 P tile
    const int tid  = threadIdx.x;
    const int wv   = tid >> 6;
    const int lane = tid & 63;
    const int g    = lane >> 4, c16 = lane & 15;
    const int n0   = (blockIdx.x >> 1) * 64 + wv * 16;
    const int d0   = (blockIdx.x & 1) * 256;

    // Q fragments (A-layout: row = lane&15, k = (lane>>4)*8 + e), hoisted for all k
    f16x8 q[4];
    #pragma unroll
    for (int kk = 0; kk < 4; ++kk)
        q[kk] = *(const f16x8*)(F16 + (n0 + c16) * CCH + kk * 32 + g * 8);

    f32x4 o[16];
    #pragma unroll
    for (int fi = 0; fi < 16; ++fi) o[fi] = 0.0f;
    float m_run[4], l_run[4];
    #pragma unroll
    for (int r = 0; r < 4; ++r) { m_run[r] = -1e30f; l_run[r] = 0.0f; }

    const _Float16* kbase = F16 + c16 * CCH + g * 8;
    const _Float16* vbase = Vt + (size_t)(d0 + c16) * NS + g * 8;
    _Float16*       pw = plds + wv * 1024 + (g * 4) * 64 + c16;
    const _Float16* pr = plds + wv * 1024 + c16 * 64 + g * 8;

    for (int t = 0; t < 144; ++t) {
        const int m0 = t * 64;

        // S = Q . K^T   (B-layout: col = lane&15 -> key index, k = channels)
        f32x4 s[4];
        #pragma unroll
        for (int cf = 0; cf < 4; ++cf) s[cf] = 0.0f;
        const _Float16* kp = kbase + m0 * CCH;
        #pragma unroll
        for (int cf = 0; cf < 4; ++cf)
            #pragma unroll
            for (int kk = 0; kk < 4; ++kk)
                s[cf] = __builtin_amdgcn_mfma_f32_16x16x32_f16(
                            q[kk], *(const f16x8*)(kp + cf * 16 * CCH + kk * 32), s[cf], 0, 0, 0);

        float cs[4];
        #pragma unroll
        for (int cf = 0; cf < 4; ++cf) cs[cf] = csv[m0 + cf * 16 + c16];

        // scale + mask; per-row tile max (rows live in 16-lane groups)
        float sv[4][4], tm[4];
        #pragma unroll
        for (int r = 0; r < 4; ++r) tm[r] = -1e30f;
        #pragma unroll
        for (int cf = 0; cf < 4; ++cf)
            #pragma unroll
            for (int r = 0; r < 4; ++r) {
                float val = (cs[cf] > 0.0f) ? s[cf][r] * cs[cf] : -1e30f;
                sv[cf][r] = val;
                tm[r] = fmaxf(tm[r], val);
            }
        #pragma unroll
        for (int r = 0; r < 4; ++r)
            #pragma unroll
            for (int off = 1; off <= 8; off <<= 1)
                tm[r] = fmaxf(tm[r], __shfl_xor(tm[r], off));

        // defer-max: rescale only when tile max exceeds running max by > 8
        bool need = false;
        #pragma unroll
        for (int r = 0; r < 4; ++r) need = need || (tm[r] > m_run[r] + 8.0f);
        if (__any(need)) {
            #pragma unroll
            for (int r = 0; r < 4; ++r) {
                float nm = fmaxf(m_run[r], tm[r]);
                float al = __expf(m_run[r] - nm);
                l_run[r] *= al; m_run[r] = nm;
                #pragma unroll
                for (int fi = 0; fi < 16; ++fi) o[fi][r] *= al;
            }
        }

        // P = exp(sv - m_run)  (masked -> exactly 0), row-sum, stash to LDS (f16)
        float ps[4] = {0.0f, 0.0f, 0.0f, 0.0f};
        #pragma unroll
        for (int cf = 0; cf < 4; ++cf)
            #pragma unroll
            for (int r = 0; r < 4; ++r) {
                float e = (cs[cf] > 0.0f) ? __expf(sv[cf][r] - m_run[r]) : 0.0f;
                ps[r] += e;
                pw[r * 64 + cf * 16] = (_Float16)e;
            }
        #pragma unroll
        for (int r = 0; r < 4; ++r) {
            #pragma unroll
            for (int off = 1; off <= 8; off <<= 1)
                ps[r] += __shfl_xor(ps[r], off);
            l_run[r] += ps[r];
        }

        // O += P . V   (wave-private LDS round-trip: C-layout -> A-layout, no barrier)
        f16x8 pa0 = *(const f16x8*)(pr);
        f16x8 pa1 = *(const f16x8*)(pr + 32);
        const _Float16* vp = vbase + m0;
        #pragma unroll
        for (int fi = 0; fi < 16; ++fi) {
            o[fi] = __builtin_amdgcn_mfma_f32_16x16x32_f16(
                        pa0, *(const f16x8*)(vp + fi * 16 * NS), o[fi], 0, 0, 0);
            o[fi] = __builtin_amdgcn_mfma_f32_16x16x32_f16(
                        pa1, *(const f16x8*)(vp + fi * 16 * NS + 32), o[fi], 0, 0, 0);
        }
    }

    float inv[4];
    #pragma unroll
    for (int r = 0; r < 4; ++r) inv[r] = 1.0f / l_run[r];
    #pragma unroll
    for (int fi = 0; fi < 16; ++fi) {
        f32x4 res;
        #pragma unroll
        for (int r = 0; r < 4; ++r) res[r] = o[fi][r] * inv[r];
        *(f32x4*)(recon_t + (size_t)(d0 + fi * 16 + c16) * NS + n0 + g * 4) = res;
    }
}

// ---------- final blend: out = x*(1-mask) + recon*mask ----------
__global__ __launch_bounds__(192) void combine_kernel(const float* __restrict__ x,
        const float* __restrict__ mask, const float* __restrict__ recon_t,
        float* __restrict__ out)
{
    int i = blockIdx.x;      // 0..95
    int c = blockIdx.y;      // 0..127
    int w = threadIdx.x;     // 0..191
    int n = i * 96 + (w >> 1);
    #pragma unroll
    for (int di = 0; di < 2; ++di) {
        int h = 2 * i + di;
        int d = c * 4 + di * 2 + (w & 1);
        float rv = recon_t[(size_t)d * NS + n];
        float xv = x[c * HW + h * W_ + w];
        float mv = mask[h * W_ + w];
        out[c * HW + h * W_ + w] = xv * (1.0f - mv) + rv * mv;
    }
}

extern "C" void kernel_launch(void* const* d_in, const int* in_sizes, int n_in,
                              void* d_out, int out_size, void* d_ws, size_t ws_size,
                              hipStream_t stream) {
    const float* x    = (const float*)d_in[0];
    const float* mask = (const float*)d_in[1];
    float* out = (float*)d_out;

    char* ws = (char*)d_ws;
    _Float16* Vt      = (_Float16*)(ws);                 //  9,437,184 B
    _Float16* F16     = (_Float16*)(ws + 9437184);       //  2,359,296 B
    float*    csv     = (float*)   (ws + 11796480);      //     36,864 B
    float*    recon_t = (float*)   (ws + 11833344);      // 18,874,368 B  (total ~30.7 MB)

    prep_vt_kernel <<<dim3(36, 512), 256, 0, stream>>>(x, Vt, F16);
    prep_csv_kernel<<<NS, 64, 0, stream>>>(F16, mask, csv);
    flash_kernel   <<<288, 256, 0, stream>>>(F16, Vt, csv, recon_t);
    combine_kernel <<<dim3(96, 128), 192, 0, stream>>>(x, mask, recon_t, out);
}

// Round 2
// 1002.109 us; speedup vs baseline: 1.5322x; 1.5322x over previous
//
#include <hip/hip_runtime.h>
#include <hip/hip_bf16.h>

typedef _Float16 f16x8 __attribute__((ext_vector_type(8)));
typedef _Float16 f16x4 __attribute__((ext_vector_type(4)));
typedef float    f32x4 __attribute__((ext_vector_type(4)));

#define HW   36864   // 192*192
#define W_   192
#define NS   9216    // 96*96 patches
#define CCH  128     // channels (QK inner dim)
#define DV   512     // c*r*r  (PV output dim)

// ---------- prep: Vt[d][m] (f16, transposed patches) + F16[m][c] (f16 feat) ----------
__global__ __launch_bounds__(256) void prep_vt_kernel(const float* __restrict__ x,
        _Float16* __restrict__ Vt, _Float16* __restrict__ F16)
{
    int m = blockIdx.x * 256 + threadIdx.x;   // 0..9215
    int d = blockIdx.y;                       // 0..511
    int c = d >> 2, di = (d >> 1) & 1, dj = d & 1;
    int i = m / 96, j = m - i * 96;
    float v = x[c * HW + (2 * i + di) * W_ + (2 * j + dj)];
    _Float16 h = (_Float16)v;
    Vt[(size_t)d * NS + m] = h;
    if ((d & 3) == 0) F16[m * CCH + c] = h;   // di=dj=0 element == feat
}

// ---------- prep: csv[m] = valid ? 10/(||f_m||+eps) : 0 ----------
__global__ __launch_bounds__(64) void prep_csv_kernel(const _Float16* __restrict__ F16,
        const float* __restrict__ mask, float* __restrict__ csv)
{
    int m = blockIdx.x;
    int t = threadIdx.x;                      // one wave
    float a = (float)F16[m * CCH + 2 * t];
    float b = (float)F16[m * CCH + 2 * t + 1];
    float ss = a * a + b * b;
    #pragma unroll
    for (int off = 1; off <= 32; off <<= 1)
        ss += __shfl_xor(ss, off);
    if (t == 0) {
        int i = m / 96, j = m - i * 96;
        float ms = mask[(2 * i) * W_ + 2 * j];
        csv[m] = (ms == 0.0f) ? 10.0f / (sqrtf(ss) + 1e-8f) : 0.0f;
    }
}

// ---------- fused masked attention, key-split flash (f16 MFMA) ----------
// grid (288, S): x = rowgroup*2 + d-half, y = key-split. 4 waves: 16 rows x 256 d each.
// Writes normalized partial O (f16) + per-row logsumexp a = m + log(l).
template<int S>
__global__ __launch_bounds__(256, 4) void flash_kernel(const _Float16* __restrict__ F16,
        const _Float16* __restrict__ Vt, const float* __restrict__ csv,
        _Float16* __restrict__ po, float* __restrict__ av)
{
    constexpr int KT = 144 / S;               // key tiles per split
    __shared__ _Float16 plds[4 * 16 * 64];    // per-wave private 16x64 P tile
    const int tid  = threadIdx.x;
    const int wv   = tid >> 6;
    const int lane = tid & 63;
    const int g    = lane >> 4, c16 = lane & 15;
    const int n0   = (blockIdx.x >> 1) * 64 + wv * 16;
    const int d0   = (blockIdx.x & 1) * 256;
    const int sp   = blockIdx.y;

    // Q fragments (A-layout: row = lane&15, k = (lane>>4)*8 + e), hoisted for all k
    f16x8 q[4];
    #pragma unroll
    for (int kk = 0; kk < 4; ++kk)
        q[kk] = *(const f16x8*)(F16 + (n0 + c16) * CCH + kk * 32 + g * 8);

    f32x4 o[16];
    #pragma unroll
    for (int fi = 0; fi < 16; ++fi) o[fi] = 0.0f;
    float m_run[4], l_run[4];
    #pragma unroll
    for (int r = 0; r < 4; ++r) { m_run[r] = -1e30f; l_run[r] = 0.0f; }

    const _Float16* kbase = F16 + c16 * CCH + g * 8;
    const _Float16* vbase = Vt + (size_t)(d0 + c16) * NS + g * 8;
    _Float16*       pw = plds + wv * 1024 + (g * 4) * 64 + c16;
    const _Float16* pr = plds + wv * 1024 + c16 * 64 + g * 8;

    for (int t = sp * KT; t < sp * KT + KT; ++t) {
        const int m0 = t * 64;

        // S = Q . K^T   (B-layout: col = lane&15 -> key index, k = channels)
        f32x4 s[4];
        #pragma unroll
        for (int cf = 0; cf < 4; ++cf) s[cf] = 0.0f;
        const _Float16* kp = kbase + m0 * CCH;
        #pragma unroll
        for (int cf = 0; cf < 4; ++cf)
            #pragma unroll
            for (int kk = 0; kk < 4; ++kk)
                s[cf] = __builtin_amdgcn_mfma_f32_16x16x32_f16(
                            q[kk], *(const f16x8*)(kp + cf * 16 * CCH + kk * 32), s[cf], 0, 0, 0);

        float cs[4];
        #pragma unroll
        for (int cf = 0; cf < 4; ++cf) cs[cf] = csv[m0 + cf * 16 + c16];

        // scale + mask; per-row tile max (rows live per (g, r), reduce across c16)
        float sv[4][4], tm[4];
        #pragma unroll
        for (int r = 0; r < 4; ++r) tm[r] = -1e30f;
        #pragma unroll
        for (int cf = 0; cf < 4; ++cf)
            #pragma unroll
            for (int r = 0; r < 4; ++r) {
                float val = (cs[cf] > 0.0f) ? s[cf][r] * cs[cf] : -1e30f;
                sv[cf][r] = val;
                tm[r] = fmaxf(tm[r], val);
            }
        #pragma unroll
        for (int r = 0; r < 4; ++r)
            #pragma unroll
            for (int off = 1; off <= 8; off <<= 1)
                tm[r] = fmaxf(tm[r], __shfl_xor(tm[r], off));

        // defer-max: rescale only when tile max exceeds running max by > 8
        bool need = false;
        #pragma unroll
        for (int r = 0; r < 4; ++r) need = need || (tm[r] > m_run[r] + 8.0f);
        if (__any(need)) {
            #pragma unroll
            for (int r = 0; r < 4; ++r) {
                float nm = fmaxf(m_run[r], tm[r]);
                float al = __expf(m_run[r] - nm);
                l_run[r] *= al; m_run[r] = nm;
                #pragma unroll
                for (int fi = 0; fi < 16; ++fi) o[fi][r] *= al;
            }
        }

        // P = exp(sv - m_run)  (masked -> exactly 0), row-sum, stash to LDS (f16)
        float ps[4] = {0.0f, 0.0f, 0.0f, 0.0f};
        #pragma unroll
        for (int cf = 0; cf < 4; ++cf)
            #pragma unroll
            for (int r = 0; r < 4; ++r) {
                float e = (cs[cf] > 0.0f) ? __expf(sv[cf][r] - m_run[r]) : 0.0f;
                ps[r] += e;
                pw[r * 64 + cf * 16] = (_Float16)e;
            }
        #pragma unroll
        for (int r = 0; r < 4; ++r) {
            #pragma unroll
            for (int off = 1; off <= 8; off <<= 1)
                ps[r] += __shfl_xor(ps[r], off);
            l_run[r] += ps[r];
        }

        // O += P . V   (wave-private LDS round-trip: C-layout -> A-layout, no barrier)
        f16x8 pa0 = *(const f16x8*)(pr);
        f16x8 pa1 = *(const f16x8*)(pr + 32);
        const _Float16* vp = vbase + m0;
        #pragma unroll
        for (int fi = 0; fi < 16; ++fi) {
            o[fi] = __builtin_amdgcn_mfma_f32_16x16x32_f16(
                        pa0, *(const f16x8*)(vp + fi * 16 * NS), o[fi], 0, 0, 0);
            o[fi] = __builtin_amdgcn_mfma_f32_16x16x32_f16(
                        pa1, *(const f16x8*)(vp + fi * 16 * NS + 32), o[fi], 0, 0, 0);
        }
    }

    // epilogue: normalized partial O (f16) + per-row a = m + log(l)
    float inv[4];
    #pragma unroll
    for (int r = 0; r < 4; ++r) inv[r] = (l_run[r] > 0.0f) ? 1.0f / l_run[r] : 0.0f;
    #pragma unroll
    for (int fi = 0; fi < 16; ++fi) {
        f16x4 res;
        #pragma unroll
        for (int r = 0; r < 4; ++r) res[r] = (_Float16)(o[fi][r] * inv[r]);
        *(f16x4*)(po + ((size_t)sp * DV + d0 + fi * 16 + c16) * NS + n0 + g * 4) = res;
    }
    if (d0 == 0 && c16 == 0) {
        #pragma unroll
        for (int r = 0; r < 4; ++r)
            av[sp * NS + n0 + g * 4 + r] =
                (l_run[r] > 0.0f) ? m_run[r] + __logf(l_run[r]) : -1e30f;
    }
}

// ---------- final: merge splits (logsumexp weights) + mask blend ----------
template<int S>
__global__ __launch_bounds__(192) void combine_kernel(const float* __restrict__ x,
        const float* __restrict__ mask, const _Float16* __restrict__ po,
        const float* __restrict__ av, float* __restrict__ out)
{
    int i = blockIdx.x;      // 0..95
    int c = blockIdx.y;      // 0..127
    int w = threadIdx.x;     // 0..191
    int n = i * 96 + (w >> 1);

    float A = -1e30f;
    #pragma unroll
    for (int s = 0; s < S; ++s) A = fmaxf(A, av[s * NS + n]);
    float wt[S], wsum = 0.0f;
    #pragma unroll
    for (int s = 0; s < S; ++s) {
        float a = av[s * NS + n];
        float e = (a > -1e29f) ? __expf(a - A) : 0.0f;
        wt[s] = e; wsum += e;
    }
    float invw = (wsum > 0.0f) ? 1.0f / wsum : 0.0f;

    #pragma unroll
    for (int di = 0; di < 2; ++di) {
        int h = 2 * i + di;
        int d = c * 4 + di * 2 + (w & 1);
        float rv = 0.0f;
        #pragma unroll
        for (int s = 0; s < S; ++s)
            rv += wt[s] * (float)po[((size_t)s * DV + d) * NS + n];
        rv *= invw;
        float xv = x[c * HW + h * W_ + w];
        float mv = mask[h * W_ + w];
        out[c * HW + h * W_ + w] = xv * (1.0f - mv) + rv * mv;
    }
}

extern "C" void kernel_launch(void* const* d_in, const int* in_sizes, int n_in,
                              void* d_out, int out_size, void* d_ws, size_t ws_size,
                              hipStream_t stream) {
    const float* x    = (const float*)d_in[0];
    const float* mask = (const float*)d_in[1];
    float* out = (float*)d_out;

    char* ws = (char*)d_ws;
    _Float16* Vt  = (_Float16*)(ws);                     //  9,437,184 B
    _Float16* F16 = (_Float16*)(ws + 9437184);           //  2,359,296 B
    float*    csv = (float*)   (ws + 11796480);          //     36,864 B
    float*    av  = (float*)   (ws + 11833344);          //    294,912 B (8 splits max)
    _Float16* po  = (_Float16*)(ws + 12128256);          //  S * 9,437,184 B

    const size_t base = 12128256ull;
    int S;
    if      (ws_size >= base + 8ull * 9437184ull) S = 8;
    else if (ws_size >= base + 4ull * 9437184ull) S = 4;
    else if (ws_size >= base + 2ull * 9437184ull) S = 2;
    else                                          S = 1;

    prep_vt_kernel <<<dim3(36, 512), 256, 0, stream>>>(x, Vt, F16);
    prep_csv_kernel<<<NS, 64, 0, stream>>>(F16, mask, csv);

    switch (S) {
    case 8:
        flash_kernel<8><<<dim3(288, 8), 256, 0, stream>>>(F16, Vt, csv, po, av);
        combine_kernel<8><<<dim3(96, 128), 192, 0, stream>>>(x, mask, po, av, out);
        break;
    case 4:
        flash_kernel<4><<<dim3(288, 4), 256, 0, stream>>>(F16, Vt, csv, po, av);
        combine_kernel<4><<<dim3(96, 128), 192, 0, stream>>>(x, mask, po, av, out);
        break;
    case 2:
        flash_kernel<2><<<dim3(288, 2), 256, 0, stream>>>(F16, Vt, csv, po, av);
        combine_kernel<2><<<dim3(96, 128), 192, 0, stream>>>(x, mask, po, av, out);
        break;
    default:
        flash_kernel<1><<<dim3(288, 1), 256, 0, stream>>>(F16, Vt, csv, po, av);
        combine_kernel<1><<<dim3(96, 128), 192, 0, stream>>>(x, mask, po, av, out);
        break;
    }
}

// Round 3
// 450.432 us; speedup vs baseline: 3.4088x; 2.2248x over previous
//
#include <hip/hip_runtime.h>
#include <hip/hip_bf16.h>

typedef _Float16 f16x8 __attribute__((ext_vector_type(8)));
typedef _Float16 f16x4 __attribute__((ext_vector_type(4)));
typedef float    f32x4 __attribute__((ext_vector_type(4)));

#define HW   36864   // 192*192
#define W_   192
#define NS   9216    // 96*96 patches
#define CCH  128     // channels (QK inner dim)
#define DV   512     // c*r*r  (PV output dim)
#define ROWS 128     // query rows per block
#define KV   64      // keys per tile
#define NT   144     // total key tiles
#define SPL  8       // key splits
#define KT   (NT / SPL)

// ---------- prep: Vt[d][m] (f16, transposed patches) + F16[m][c] (f16 feat) ----------
__global__ __launch_bounds__(256) void prep_vt_kernel(const float* __restrict__ x,
        _Float16* __restrict__ Vt, _Float16* __restrict__ F16)
{
    int m = blockIdx.x * 256 + threadIdx.x;   // 0..9215
    int d = blockIdx.y;                       // 0..511
    int c = d >> 2, di = (d >> 1) & 1, dj = d & 1;
    int i = m / 96, j = m - i * 96;
    float v = x[c * HW + (2 * i + di) * W_ + (2 * j + dj)];
    _Float16 h = (_Float16)v;
    Vt[(size_t)d * NS + m] = h;
    if ((d & 3) == 0) F16[m * CCH + c] = h;   // di=dj=0 element == feat
}

// ---------- prep: csv[m] = valid ? 10/(||f_m||+eps) : 0 ----------
__global__ __launch_bounds__(64) void prep_csv_kernel(const _Float16* __restrict__ F16,
        const float* __restrict__ mask, float* __restrict__ csv)
{
    int m = blockIdx.x;
    int t = threadIdx.x;                      // one wave
    float a = (float)F16[m * CCH + 2 * t];
    float b = (float)F16[m * CCH + 2 * t + 1];
    float ss = a * a + b * b;
    #pragma unroll
    for (int off = 1; off <= 32; off <<= 1)
        ss += __shfl_xor(ss, off);
    if (t == 0) {
        int i = m / 96, j = m - i * 96;
        float ms = mask[(2 * i) * W_ + 2 * j];
        csv[m] = (ms == 0.0f) ? 10.0f / (sqrtf(ss) + 1e-8f) : 0.0f;
    }
}

// ---------- fused masked attention: 128-row blocks, LDS-shared K and P ----------
// 8 waves. Wave w: QK role = rowgroup w (16 rows), PV role = d-slice w (64 d, all 128 rows).
__global__ __launch_bounds__(512, 2) void flash_kernel(const _Float16* __restrict__ F16,
        const _Float16* __restrict__ Vt, const float* __restrict__ csv,
        _Float16* __restrict__ po, float* __restrict__ av)
{
    __shared__ _Float16 Kbuf[2][KV * CCH];    // 2 x 16 KB, [key][slot16B ^ (key&7)]
    __shared__ _Float16 Pbuf[2][ROWS * KV];   // 2 x 16 KB, [row][slot16B ^ (row&7)]
    __shared__ float    abuf[2][ROWS];        // per-tile O-rescale factors
    __shared__ float    lbuf[ROWS];           // final 1/l
    __shared__ int      flagbuf[KT];          // per-tile rescale flag

    const int tid  = threadIdx.x;
    const int wv   = tid >> 6;
    const int lane = tid & 63;
    const int g    = lane >> 4, c16 = lane & 15;
    const int n0   = blockIdx.x * ROWS;
    const int sp   = blockIdx.y;
    const int t0   = sp * KT;

    if (tid < KT) flagbuf[tid] = 0;

    // Q A-frags for this wave's QK rowgroup (row = n0 + wv*16 + c16)
    f16x8 q[4];
    #pragma unroll
    for (int kk = 0; kk < 4; ++kk)
        q[kk] = *(const f16x8*)(F16 + (n0 + wv * 16 + c16) * CCH + kk * 32 + g * 8);

    f32x4 o[8][4];
    #pragma unroll
    for (int rf = 0; rf < 8; ++rf)
        #pragma unroll
        for (int df = 0; df < 4; ++df) o[rf][df] = 0.0f;
    float m_run[4], l_run[4];
    #pragma unroll
    for (int r = 0; r < 4; ++r) { m_run[r] = -1e30f; l_run[r] = 0.0f; }

    // K staging assignment: thread stages 32 B of key row (tid>>3), slots (tid&7)*2, +1
    const int kkey = tid >> 3;
    const int ksl  = (tid & 7) * 2;

    // prologue: stage K tile t0 into Kbuf[0]
    {
        const _Float16* ks = F16 + (size_t)(t0 * KV + kkey) * CCH + (tid & 7) * 16;
        f16x8 k0 = *(const f16x8*)(ks);
        f16x8 k1 = *(const f16x8*)(ks + 8);
        *(f16x8*)(&Kbuf[0][kkey * CCH + ((ksl ^ (kkey & 7)) * 8)])       = k0;
        *(f16x8*)(&Kbuf[0][kkey * CCH + (((ksl + 1) ^ (kkey & 7)) * 8)]) = k1;
    }
    asm volatile("s_waitcnt lgkmcnt(0)" ::: "memory");
    __builtin_amdgcn_s_barrier();

    for (int tl = 0; tl < KT; ++tl) {
        const int buf = tl & 1;
        const int m0  = (t0 + tl) * KV;

        // K prefetch (regs) for next tile — written to LDS later this iter
        f16x8 k0, k1;
        const bool havek = (tl + 1 < KT);
        if (havek) {
            const _Float16* ks = F16 + (size_t)((t0 + tl + 1) * KV + kkey) * CCH + (tid & 7) * 16;
            k0 = *(const f16x8*)(ks);
            k1 = *(const f16x8*)(ks + 8);
        }
        // V B-frags for this tile (global; latency hides under QK+softmax)
        f16x8 vreg[8];
        #pragma unroll
        for (int kf = 0; kf < 2; ++kf)
            #pragma unroll
            for (int df = 0; df < 4; ++df)
                vreg[kf * 4 + df] = *(const f16x8*)(Vt
                    + (size_t)(wv * 64 + df * 16 + c16) * NS + m0 + kf * 32 + g * 8);

        // ---- QK^T from swizzled Kbuf ----
        f32x4 s[4];
        #pragma unroll
        for (int cf = 0; cf < 4; ++cf) s[cf] = 0.0f;
        #pragma unroll
        for (int cf = 0; cf < 4; ++cf) {
            const int key = cf * 16 + c16;
            const _Float16* kr = &Kbuf[buf][key * CCH];
            const int sw = key & 7;
            #pragma unroll
            for (int kk = 0; kk < 4; ++kk)
                s[cf] = __builtin_amdgcn_mfma_f32_16x16x32_f16(
                            q[kk], *(const f16x8*)(kr + (((kk * 4 + g) ^ sw) * 8)), s[cf], 0, 0, 0);
        }

        float cs[4];
        #pragma unroll
        for (int cf = 0; cf < 4; ++cf) cs[cf] = csv[m0 + cf * 16 + c16];

        // scale + mask; per-row tile max (row = g*4+r, reduce across c16 lanes)
        float sv[4][4], tm[4];
        #pragma unroll
        for (int r = 0; r < 4; ++r) tm[r] = -1e30f;
        #pragma unroll
        for (int cf = 0; cf < 4; ++cf)
            #pragma unroll
            for (int r = 0; r < 4; ++r) {
                float val = (cs[cf] > 0.0f) ? s[cf][r] * cs[cf] : -1e30f;
                sv[cf][r] = val;
                tm[r] = fmaxf(tm[r], val);
            }
        #pragma unroll
        for (int r = 0; r < 4; ++r)
            #pragma unroll
            for (int off = 1; off <= 8; off <<= 1)
                tm[r] = fmaxf(tm[r], __shfl_xor(tm[r], off));

        // defer-max; α broadcast via LDS (O rescale is applied by PV role of ALL waves)
        float al[4] = {1.0f, 1.0f, 1.0f, 1.0f};
        bool need = false;
        #pragma unroll
        for (int r = 0; r < 4; ++r) need = need || (tm[r] > m_run[r] + 8.0f);
        const bool wneed = __any(need);
        if (wneed) {
            #pragma unroll
            for (int r = 0; r < 4; ++r) {
                float nm = fmaxf(m_run[r], tm[r]);
                al[r] = __expf(m_run[r] - nm);
                l_run[r] *= al[r]; m_run[r] = nm;
            }
            if (lane == 0) flagbuf[tl] = 1;
        }
        if (c16 == 0) {
            #pragma unroll
            for (int r = 0; r < 4; ++r) abuf[buf][wv * 16 + g * 4 + r] = al[r];
        }

        // P = exp(sv - m_run) (masked -> 0), row-sum, write swizzled Pbuf (f16)
        float ps[4] = {0.0f, 0.0f, 0.0f, 0.0f};
        #pragma unroll
        for (int cf = 0; cf < 4; ++cf)
            #pragma unroll
            for (int r = 0; r < 4; ++r) {
                float e = (cs[cf] > 0.0f) ? __expf(sv[cf][r] - m_run[r]) : 0.0f;
                ps[r] += e;
                const int row = g * 4 + r, key = cf * 16 + c16;
                Pbuf[buf][(wv * 16 + row) * KV + (((key >> 3) ^ (row & 7)) * 8) + (key & 7)]
                    = (_Float16)e;
            }
        #pragma unroll
        for (int r = 0; r < 4; ++r) {
            #pragma unroll
            for (int off = 1; off <= 8; off <<= 1)
                ps[r] += __shfl_xor(ps[r], off);
            l_run[r] += ps[r];
        }

        // stash prefetched K tile (other buffer)
        if (havek) {
            const int nb = buf ^ 1;
            *(f16x8*)(&Kbuf[nb][kkey * CCH + ((ksl ^ (kkey & 7)) * 8)])       = k0;
            *(f16x8*)(&Kbuf[nb][kkey * CCH + (((ksl + 1) ^ (kkey & 7)) * 8)]) = k1;
        }

        asm volatile("s_waitcnt lgkmcnt(0)" ::: "memory");
        __builtin_amdgcn_s_barrier();

        // ---- PV: O[128 rows][64 d] for this wave's d-slice ----
        if (flagbuf[tl]) {
            #pragma unroll
            for (int rf = 0; rf < 8; ++rf) {
                f32x4 a4 = *(const f32x4*)(&abuf[buf][rf * 16 + g * 4]);
                #pragma unroll
                for (int df = 0; df < 4; ++df)
                    #pragma unroll
                    for (int r = 0; r < 4; ++r) o[rf][df][r] *= a4[r];
            }
        }
        #pragma unroll
        for (int kf = 0; kf < 2; ++kf) {
            f16x8 pa[8];
            #pragma unroll
            for (int rf = 0; rf < 8; ++rf) {
                const int row = rf * 16 + c16;
                pa[rf] = *(const f16x8*)(&Pbuf[buf][row * KV + (((kf * 4 + g) ^ (row & 7)) * 8)]);
            }
            #pragma unroll
            for (int df = 0; df < 4; ++df)
                #pragma unroll
                for (int rf = 0; rf < 8; ++rf)
                    o[rf][df] = __builtin_amdgcn_mfma_f32_16x16x32_f16(
                                    pa[rf], vreg[kf * 4 + df], o[rf][df], 0, 0, 0);
        }
    }

    // epilogue: share 1/l across waves; write normalized partial O (f16) + logsumexp
    if (c16 == 0) {
        #pragma unroll
        for (int r = 0; r < 4; ++r) {
            lbuf[wv * 16 + g * 4 + r] = (l_run[r] > 0.0f) ? 1.0f / l_run[r] : 0.0f;
            av[sp * NS + n0 + wv * 16 + g * 4 + r] =
                (l_run[r] > 0.0f) ? m_run[r] + __logf(l_run[r]) : -1e30f;
        }
    }
    asm volatile("s_waitcnt lgkmcnt(0)" ::: "memory");
    __builtin_amdgcn_s_barrier();

    #pragma unroll
    for (int rf = 0; rf < 8; ++rf) {
        f32x4 li = *(const f32x4*)(&lbuf[rf * 16 + g * 4]);
        #pragma unroll
        for (int df = 0; df < 4; ++df) {
            f16x4 res;
            #pragma unroll
            for (int r = 0; r < 4; ++r) res[r] = (_Float16)(o[rf][df][r] * li[r]);
            *(f16x4*)(po + ((size_t)sp * DV + wv * 64 + df * 16 + c16) * NS
                          + n0 + rf * 16 + g * 4) = res;
        }
    }
}

// ---------- final: merge splits (logsumexp weights) + mask blend ----------
template<int S>
__global__ __launch_bounds__(192) void combine_kernel(const float* __restrict__ x,
        const float* __restrict__ mask, const _Float16* __restrict__ po,
        const float* __restrict__ av, float* __restrict__ out)
{
    int i = blockIdx.x;      // 0..95
    int c = blockIdx.y;      // 0..127
    int w = threadIdx.x;     // 0..191
    int n = i * 96 + (w >> 1);

    float A = -1e30f;
    #pragma unroll
    for (int s = 0; s < S; ++s) A = fmaxf(A, av[s * NS + n]);
    float wt[S], wsum = 0.0f;
    #pragma unroll
    for (int s = 0; s < S; ++s) {
        float a = av[s * NS + n];
        float e = (a > -1e29f) ? __expf(a - A) : 0.0f;
        wt[s] = e; wsum += e;
    }
    float invw = (wsum > 0.0f) ? 1.0f / wsum : 0.0f;

    #pragma unroll
    for (int di = 0; di < 2; ++di) {
        int h = 2 * i + di;
        int d = c * 4 + di * 2 + (w & 1);
        float rv = 0.0f;
        #pragma unroll
        for (int s = 0; s < S; ++s)
            rv += wt[s] * (float)po[((size_t)s * DV + d) * NS + n];
        rv *= invw;
        float xv = x[c * HW + h * W_ + w];
        float mv = mask[h * W_ + w];
        out[c * HW + h * W_ + w] = xv * (1.0f - mv) + rv * mv;
    }
}

extern "C" void kernel_launch(void* const* d_in, const int* in_sizes, int n_in,
                              void* d_out, int out_size, void* d_ws, size_t ws_size,
                              hipStream_t stream) {
    const float* x    = (const float*)d_in[0];
    const float* mask = (const float*)d_in[1];
    float* out = (float*)d_out;

    char* ws = (char*)d_ws;
    _Float16* Vt  = (_Float16*)(ws);                     //  9,437,184 B
    _Float16* F16 = (_Float16*)(ws + 9437184);           //  2,359,296 B
    float*    csv = (float*)   (ws + 11796480);          //     36,864 B
    float*    av  = (float*)   (ws + 11833344);          //    294,912 B
    _Float16* po  = (_Float16*)(ws + 12128256);          //  8 * 9,437,184 B

    prep_vt_kernel <<<dim3(36, 512), 256, 0, stream>>>(x, Vt, F16);
    prep_csv_kernel<<<NS, 64, 0, stream>>>(F16, mask, csv);
    flash_kernel   <<<dim3(NS / ROWS, SPL), 512, 0, stream>>>(F16, Vt, csv, po, av);
    combine_kernel<SPL><<<dim3(96, 128), 192, 0, stream>>>(x, mask, po, av, out);
}

// Round 4
// 317.717 us; speedup vs baseline: 4.8327x; 1.4177x over previous
//
#include <hip/hip_runtime.h>
#include <hip/hip_bf16.h>

typedef _Float16 f16x8 __attribute__((ext_vector_type(8)));
typedef _Float16 f16x4 __attribute__((ext_vector_type(4)));
typedef float    f32x4 __attribute__((ext_vector_type(4)));

#define HW   36864   // 192*192
#define W_   192
#define NS   9216    // 96*96 patches
#define CCH  128     // channels (QK inner dim)
#define DV   512     // c*r*r  (PV output dim)
#define ROWS 64      // query rows per block
#define KV   64      // keys per tile
#define NT   144     // total key tiles
#define SPL  4       // key splits
#define KT   (NT / SPL)

// ---------- prep: Vt[d][m] (f16, transposed patches) + F16[m][c] (f16 feat) ----------
__global__ __launch_bounds__(256) void prep_vt_kernel(const float* __restrict__ x,
        _Float16* __restrict__ Vt, _Float16* __restrict__ F16)
{
    int m = blockIdx.x * 256 + threadIdx.x;   // 0..9215
    int d = blockIdx.y;                       // 0..511
    int c = d >> 2, di = (d >> 1) & 1, dj = d & 1;
    int i = m / 96, j = m - i * 96;
    float v = x[c * HW + (2 * i + di) * W_ + (2 * j + dj)];
    _Float16 h = (_Float16)v;
    Vt[(size_t)d * NS + m] = h;
    if ((d & 3) == 0) F16[m * CCH + c] = h;   // di=dj=0 element == feat
}

// ---------- prep: csv[m] = valid ? 10/(||f_m||+eps) : 0 ----------
__global__ __launch_bounds__(64) void prep_csv_kernel(const _Float16* __restrict__ F16,
        const float* __restrict__ mask, float* __restrict__ csv)
{
    int m = blockIdx.x;
    int t = threadIdx.x;                      // one wave
    float a = (float)F16[m * CCH + 2 * t];
    float b = (float)F16[m * CCH + 2 * t + 1];
    float ss = a * a + b * b;
    #pragma unroll
    for (int off = 1; off <= 32; off <<= 1)
        ss += __shfl_xor(ss, off);
    if (t == 0) {
        int i = m / 96, j = m - i * 96;
        float ms = mask[(2 * i) * W_ + 2 * j];
        csv[m] = (ms == 0.0f) ? 10.0f / (sqrtf(ss) + 1e-8f) : 0.0f;
    }
}

// ---------- fused masked attention: 64-row x 256-d blocks, 4 waves ----------
// Wave w: QK role = rowgroup w (16 rows x 64 keys), PV role = d-slice w (64 d x 64 rows).
__global__ __launch_bounds__(256, 2) void flash_kernel(const _Float16* __restrict__ F16,
        const _Float16* __restrict__ Vt, const float* __restrict__ csv,
        _Float16* __restrict__ po, float* __restrict__ av)
{
    __shared__ _Float16 Kbuf[2][KV * CCH];    // 2 x 16 KB, [key][chunk16B ^ (key&7)]
    __shared__ _Float16 Pbuf[2][ROWS * KV];   // 2 x 8 KB,  [row][chunk16B ^ (row&7)]
    __shared__ float    abuf[2][ROWS];        // per-tile O-rescale factors
    __shared__ float    lbuf[ROWS];           // final 1/l
    __shared__ int      flagbuf[KT];          // per-tile rescale flag

    const int tid  = threadIdx.x;
    const int wv   = tid >> 6;
    const int lane = tid & 63;
    const int g    = lane >> 4, c16 = lane & 15;
    const int n0   = (blockIdx.x >> 1) * ROWS;
    const int d0   = (blockIdx.x & 1) * 256;
    const int sp   = blockIdx.y;
    const int t0   = sp * KT;

    if (tid < KT) flagbuf[tid] = 0;

    // Q A-frags for this wave's QK rowgroup (row = n0 + wv*16 + c16)
    f16x8 q[4];
    #pragma unroll
    for (int kk = 0; kk < 4; ++kk)
        q[kk] = *(const f16x8*)(F16 + (n0 + wv * 16 + c16) * CCH + kk * 32 + g * 8);

    f32x4 o[4][4];
    #pragma unroll
    for (int rf = 0; rf < 4; ++rf)
        #pragma unroll
        for (int df = 0; df < 4; ++df) o[rf][df] = 0.0f;
    float m_run[4], l_run[4];
    #pragma unroll
    for (int r = 0; r < 4; ++r) { m_run[r] = -1e30f; l_run[r] = 0.0f; }

    // K staging: thread stages key = tid>>2, 4 chunks of 16B starting at (tid&3)*4
    const int kkey = tid >> 2;
    const int kch0 = (tid & 3) * 4;

    // prologue: stage K tile t0 into Kbuf[0]
    {
        const _Float16* ks = F16 + (size_t)(t0 * KV + kkey) * CCH + kch0 * 8;
        #pragma unroll
        for (int j = 0; j < 4; ++j)
            *(f16x8*)(&Kbuf[0][kkey * CCH + (((kch0 + j) ^ (kkey & 7)) * 8)])
                = *(const f16x8*)(ks + j * 8);
    }
    asm volatile("s_waitcnt lgkmcnt(0)" ::: "memory");
    __builtin_amdgcn_s_barrier();

    for (int tl = 0; tl < KT; ++tl) {
        const int buf = tl & 1;
        const int m0  = (t0 + tl) * KV;

        // K prefetch (regs) for next tile — ds_written before the mid-tile barrier
        f16x8 kpre[4];
        const bool havek = (tl + 1 < KT);
        if (havek) {
            const _Float16* ks = F16 + (size_t)((t0 + tl + 1) * KV + kkey) * CCH + kch0 * 8;
            #pragma unroll
            for (int j = 0; j < 4; ++j) kpre[j] = *(const f16x8*)(ks + j * 8);
        }
        // V B-frags for this tile (global; latency hides under QK+softmax)
        f16x8 vreg[8];
        #pragma unroll
        for (int kf = 0; kf < 2; ++kf)
            #pragma unroll
            for (int df = 0; df < 4; ++df)
                vreg[kf * 4 + df] = *(const f16x8*)(Vt
                    + (size_t)(d0 + wv * 64 + df * 16 + c16) * NS + m0 + kf * 32 + g * 8);

        // ---- QK^T from swizzled Kbuf ----
        f32x4 s[4];
        #pragma unroll
        for (int cf = 0; cf < 4; ++cf) s[cf] = 0.0f;
        #pragma unroll
        for (int cf = 0; cf < 4; ++cf) {
            const int key = cf * 16 + c16;
            const _Float16* kr = &Kbuf[buf][key * CCH];
            const int sw = key & 7;
            #pragma unroll
            for (int kk = 0; kk < 4; ++kk)
                s[cf] = __builtin_amdgcn_mfma_f32_16x16x32_f16(
                            q[kk], *(const f16x8*)(kr + (((kk * 4 + g) ^ sw) * 8)), s[cf], 0, 0, 0);
        }

        float cs[4];
        #pragma unroll
        for (int cf = 0; cf < 4; ++cf) cs[cf] = csv[m0 + cf * 16 + c16];

        // scale + mask; per-row tile max (row = g*4+r, reduce across c16 lanes)
        float sv[4][4], tm[4];
        #pragma unroll
        for (int r = 0; r < 4; ++r) tm[r] = -1e30f;
        #pragma unroll
        for (int cf = 0; cf < 4; ++cf)
            #pragma unroll
            for (int r = 0; r < 4; ++r) {
                float val = (cs[cf] > 0.0f) ? s[cf][r] * cs[cf] : -1e30f;
                sv[cf][r] = val;
                tm[r] = fmaxf(tm[r], val);
            }
        #pragma unroll
        for (int r = 0; r < 4; ++r)
            #pragma unroll
            for (int off = 1; off <= 8; off <<= 1)
                tm[r] = fmaxf(tm[r], __shfl_xor(tm[r], off));

        // defer-max; α broadcast via LDS (O rescale applied by PV role of ALL waves)
        float al[4] = {1.0f, 1.0f, 1.0f, 1.0f};
        bool need = false;
        #pragma unroll
        for (int r = 0; r < 4; ++r) need = need || (tm[r] > m_run[r] + 8.0f);
        if (__any(need)) {
            #pragma unroll
            for (int r = 0; r < 4; ++r) {
                float nm = fmaxf(m_run[r], tm[r]);
                al[r] = __expf(m_run[r] - nm);
                l_run[r] *= al[r]; m_run[r] = nm;
            }
            if (lane == 0) flagbuf[tl] = 1;
        }
        if (c16 == 0) {
            #pragma unroll
            for (int r = 0; r < 4; ++r) abuf[buf][wv * 16 + g * 4 + r] = al[r];
        }

        // P = exp(sv - m_run) (masked -> 0), row-sum, write swizzled Pbuf (f16)
        float ps[4] = {0.0f, 0.0f, 0.0f, 0.0f};
        #pragma unroll
        for (int cf = 0; cf < 4; ++cf)
            #pragma unroll
            for (int r = 0; r < 4; ++r) {
                float e = (cs[cf] > 0.0f) ? __expf(sv[cf][r] - m_run[r]) : 0.0f;
                ps[r] += e;
                const int row = wv * 16 + g * 4 + r, key = cf * 16 + c16;
                Pbuf[buf][row * KV + (((key >> 3) ^ (row & 7)) * 8) + (key & 7)]
                    = (_Float16)e;
            }
        #pragma unroll
        for (int r = 0; r < 4; ++r) {
            #pragma unroll
            for (int off = 1; off <= 8; off <<= 1)
                ps[r] += __shfl_xor(ps[r], off);
            l_run[r] += ps[r];
        }

        // stash prefetched K tile (other buffer)
        if (havek) {
            #pragma unroll
            for (int j = 0; j < 4; ++j)
                *(f16x8*)(&Kbuf[buf ^ 1][kkey * CCH + (((kch0 + j) ^ (kkey & 7)) * 8)])
                    = kpre[j];
        }

        asm volatile("s_waitcnt lgkmcnt(0)" ::: "memory");
        __builtin_amdgcn_s_barrier();

        // ---- PV: O[64 rows][64 d] for this wave's d-slice ----
        if (flagbuf[tl]) {
            #pragma unroll
            for (int rf = 0; rf < 4; ++rf) {
                f32x4 a4 = *(const f32x4*)(&abuf[buf][rf * 16 + g * 4]);
                #pragma unroll
                for (int df = 0; df < 4; ++df)
                    #pragma unroll
                    for (int r = 0; r < 4; ++r) o[rf][df][r] *= a4[r];
            }
        }
        #pragma unroll
        for (int kf = 0; kf < 2; ++kf) {
            f16x8 pa[4];
            #pragma unroll
            for (int rf = 0; rf < 4; ++rf) {
                const int row = rf * 16 + c16;
                pa[rf] = *(const f16x8*)(&Pbuf[buf][row * KV + (((kf * 4 + g) ^ (row & 7)) * 8)]);
            }
            #pragma unroll
            for (int df = 0; df < 4; ++df)
                #pragma unroll
                for (int rf = 0; rf < 4; ++rf)
                    o[rf][df] = __builtin_amdgcn_mfma_f32_16x16x32_f16(
                                    pa[rf], vreg[kf * 4 + df], o[rf][df], 0, 0, 0);
        }
    }

    // epilogue: share 1/l across waves; write normalized partial O (f16) + logsumexp
    if (c16 == 0) {
        #pragma unroll
        for (int r = 0; r < 4; ++r) {
            lbuf[wv * 16 + g * 4 + r] = (l_run[r] > 0.0f) ? 1.0f / l_run[r] : 0.0f;
            if (d0 == 0)
                av[sp * NS + n0 + wv * 16 + g * 4 + r] =
                    (l_run[r] > 0.0f) ? m_run[r] + __logf(l_run[r]) : -1e30f;
        }
    }
    asm volatile("s_waitcnt lgkmcnt(0)" ::: "memory");
    __builtin_amdgcn_s_barrier();

    #pragma unroll
    for (int rf = 0; rf < 4; ++rf) {
        f32x4 li = *(const f32x4*)(&lbuf[rf * 16 + g * 4]);
        #pragma unroll
        for (int df = 0; df < 4; ++df) {
            f16x4 res;
            #pragma unroll
            for (int r = 0; r < 4; ++r) res[r] = (_Float16)(o[rf][df][r] * li[r]);
            *(f16x4*)(po + ((size_t)sp * DV + d0 + wv * 64 + df * 16 + c16) * NS
                          + n0 + rf * 16 + g * 4) = res;
        }
    }
}

// ---------- final: merge splits (logsumexp weights) + mask blend ----------
template<int S>
__global__ __launch_bounds__(192) void combine_kernel(const float* __restrict__ x,
        const float* __restrict__ mask, const _Float16* __restrict__ po,
        const float* __restrict__ av, float* __restrict__ out)
{
    int i = blockIdx.x;      // 0..95
    int c = blockIdx.y;      // 0..127
    int w = threadIdx.x;     // 0..191
    int n = i * 96 + (w >> 1);

    float A = -1e30f;
    #pragma unroll
    for (int s = 0; s < S; ++s) A = fmaxf(A, av[s * NS + n]);
    float wt[S], wsum = 0.0f;
    #pragma unroll
    for (int s = 0; s < S; ++s) {
        float a = av[s * NS + n];
        float e = (a > -1e29f) ? __expf(a - A) : 0.0f;
        wt[s] = e; wsum += e;
    }
    float invw = (wsum > 0.0f) ? 1.0f / wsum : 0.0f;

    #pragma unroll
    for (int di = 0; di < 2; ++di) {
        int h = 2 * i + di;
        int d = c * 4 + di * 2 + (w & 1);
        float rv = 0.0f;
        #pragma unroll
        for (int s = 0; s < S; ++s)
            rv += wt[s] * (float)po[((size_t)s * DV + d) * NS + n];
        rv *= invw;
        float xv = x[c * HW + h * W_ + w];
        float mv = mask[h * W_ + w];
        out[c * HW + h * W_ + w] = xv * (1.0f - mv) + rv * mv;
    }
}

extern "C" void kernel_launch(void* const* d_in, const int* in_sizes, int n_in,
                              void* d_out, int out_size, void* d_ws, size_t ws_size,
                              hipStream_t stream) {
    const float* x    = (const float*)d_in[0];
    const float* mask = (const float*)d_in[1];
    float* out = (float*)d_out;

    char* ws = (char*)d_ws;
    _Float16* Vt  = (_Float16*)(ws);                     //  9,437,184 B
    _Float16* F16 = (_Float16*)(ws + 9437184);           //  2,359,296 B
    float*    csv = (float*)   (ws + 11796480);          //     36,864 B
    float*    av  = (float*)   (ws + 11833344);          //    294,912 B
    _Float16* po  = (_Float16*)(ws + 12128256);          //  4 * 9,437,184 B

    prep_vt_kernel <<<dim3(36, 512), 256, 0, stream>>>(x, Vt, F16);
    prep_csv_kernel<<<NS, 64, 0, stream>>>(F16, mask, csv);
    flash_kernel   <<<dim3(288, SPL), 256, 0, stream>>>(F16, Vt, csv, po, av);
    combine_kernel<SPL><<<dim3(96, 128), 192, 0, stream>>>(x, mask, po, av, out);
}